// Round 10
// baseline (337.253 us; speedup 1.0000x reference)
//
#include <hip/hip_runtime.h>
#include <hip/hip_bf16.h>
#include <math.h>

typedef __bf16 bf16x8 __attribute__((ext_vector_type(8)));
typedef __bf16 bf16x4 __attribute__((ext_vector_type(4)));
typedef float  f32x4  __attribute__((ext_vector_type(4)));

#define GLD16(g, l) __builtin_amdgcn_global_load_lds(                      \
    (const __attribute__((address_space(1))) void*)(g),                    \
    (__attribute__((address_space(3))) void*)(l), 16, 0, 0)

#define SCHED_FENCE() __builtin_amdgcn_sched_barrier(0)

// BK=32 LDS tiles (64 B rows): global k-group g of row r stored at slot
// g ^ ((r>>1)&3) -> all ds_read_b128 fragment reads are 2-way (free).

// ---------------- merged weight repack (was 3 kernels) ----------------------
__global__ __launch_bounds__(256) void repack_k(
    const float* __restrict__ Wq, const float* __restrict__ Wk,
    const float* __restrict__ Wv, const float* __restrict__ Wqb,
    const float* __restrict__ Wkb, const float* __restrict__ Wo,
    const float* __restrict__ W2, const float* __restrict__ W1,
    __bf16* __restrict__ Wt5, __bf16* __restrict__ WoW2t,
    __bf16* __restrict__ W1t) {
  int t = blockIdx.x;
  const float* in; __bf16* outp;
  int ldin, ldout, r0, c0, cin0, oofs;
  if (t < 5120) {
    int w = t >> 10, rem = t & 1023;
    const float* src[5] = {Wq, Wk, Wv, Wqb, Wkb};
    in = src[w]; ldin = 1024;
    r0 = (rem >> 5) << 5; c0 = (rem & 31) << 5; cin0 = c0;
    outp = Wt5 + (size_t)w * 1048576; ldout = 1024; oofs = 0;
  } else if (t < 6144) {
    int rem = t - 5120;
    in = Wo; ldin = 1024;
    r0 = (rem >> 5) << 5; c0 = (rem & 31) << 5; cin0 = c0;
    outp = WoW2t; ldout = 5120; oofs = 0;
  } else if (t < 10240) {
    int rem = t - 6144;
    in = W2; ldin = 1024;
    r0 = (rem >> 5) << 5; c0 = (rem & 31) << 5; cin0 = c0;
    outp = WoW2t; ldout = 5120; oofs = 1024;
  } else {
    int rem = t - 10240;
    in = W1; ldin = 8192;
    c0 = (rem & 255) << 5; r0 = (rem >> 8) << 5;
    cin0 = ((c0 >> 5) & 1) * 4096 + (c0 >> 6) * 32;
    outp = W1t; ldout = 1024; oofs = 0;
  }
  __shared__ float sh[32][33];
  int tid = threadIdx.x, tx = tid & 31, ty = tid >> 5;
  #pragma unroll
  for (int i = ty; i < 32; i += 8)
    sh[i][tx] = in[(size_t)(r0 + i) * ldin + cin0 + tx];
  __syncthreads();
  #pragma unroll
  for (int i = ty; i < 32; i += 8)
    outp[(size_t)(c0 + i) * ldout + oofs + r0 + tx] = (__bf16)sh[tx][i];
}

// ---------------- RMSNorm ---------------------------------------------------
__global__ __launch_bounds__(256) void rmsnorm_k(const float* __restrict__ hs,
                                                 __bf16* __restrict__ x) {
  int row = blockIdx.x, tid = threadIdx.x;
  const float4 v = ((const float4*)(hs + (size_t)row * 1024))[tid];
  float ss = v.x * v.x + v.y * v.y + v.z * v.z + v.w * v.w;
  #pragma unroll
  for (int o = 32; o > 0; o >>= 1) ss += __shfl_xor(ss, o);
  __shared__ float ps[4];
  if ((tid & 63) == 0) ps[tid >> 6] = ss;
  __syncthreads();
  float tot = ps[0] + ps[1] + ps[2] + ps[3];
  float r = rsqrtf(tot * (1.0f / 1024.0f) + 1.1920929e-7f);
  __bf16* xr = x + (size_t)row * 1024 + tid * 4;
  xr[0] = (__bf16)(v.x * r); xr[1] = (__bf16)(v.y * r);
  xr[2] = (__bf16)(v.z * r); xr[3] = (__bf16)(v.w * r);
}

// ---------------- GEMM 128x128 ring-3, 2-phase, fused l2norm/RoPE -----------
__global__ __launch_bounds__(256, 3) void gemm_qkv_k(
    const __bf16* __restrict__ A, const __bf16* __restrict__ Bt,
    __bf16* __restrict__ qbf, __bf16* __restrict__ kbf,
    float* __restrict__ qb32, float* __restrict__ kb32,
    __bf16* __restrict__ vtbf) {
  const int K = 1024;
  __shared__ __bf16 sA[3][128 * 32];
  __shared__ __bf16 sB[3][128 * 32];
  const int tid = threadIdx.x;
  const int lane = tid & 63;
  const int quad = lane >> 4, l16 = lane & 15;
  const int wave = tid >> 6;
  const int waveM = wave >> 1, waveN = wave & 1;
  const int m0 = blockIdx.y * 128, n0 = blockIdx.x * 128;
  const int nk = K >> 5;
  const int rowS = tid >> 2;
  const int kg = ((tid & 3) ^ ((rowS >> 1) & 3)) * 8;
  const __bf16* gA0 = A + (size_t)(m0 + rowS) * K + kg;
  const __bf16* gA1 = gA0 + (size_t)64 * K;
  const __bf16* gB0 = Bt + (size_t)(n0 + rowS) * K + kg;
  const __bf16* gB1 = gB0 + (size_t)64 * K;
  const int lo0 = tid * 8, lo1 = 2048 + tid * 8;

  auto stageA = [&](int t) {
    __bf16* dA = sA[t % 3];
    GLD16(gA0 + t * 32, dA + lo0);
    GLD16(gA1 + t * 32, dA + lo1);
  };
  auto stageB = [&](int t) {
    __bf16* dB = sB[t % 3];
    GLD16(gB0 + t * 32, dB + lo0);
    GLD16(gB1 + t * 32, dB + lo1);
  };
  stageA(0); stageB(0);
  stageA(1); stageB(1);

  f32x4 acc[4][4] = {};
  #pragma unroll 1
  for (int i = 0; i < nk; ++i) {
    if (i < nk - 1)
      asm volatile("s_waitcnt vmcnt(4)" ::: "memory");
    else
      asm volatile("s_waitcnt vmcnt(0)" ::: "memory");
    __builtin_amdgcn_s_barrier();
    SCHED_FENCE();
    const __bf16* cA = sA[i % 3];
    const __bf16* cB = sB[i % 3];
    // phase 0: reads (bfv + af0/1) || stage A-half of tile i+2
    bf16x8 af[4], bfv[4];
    #pragma unroll
    for (int nt = 0; nt < 4; ++nt) {
      int r = waveN * 64 + nt * 16 + l16;
      bfv[nt] = *(const bf16x8*)(cB + r * 32 + ((quad ^ ((r >> 1) & 3)) * 8));
    }
    #pragma unroll
    for (int mt = 0; mt < 2; ++mt) {
      int r = waveM * 64 + mt * 16 + l16;
      af[mt] = *(const bf16x8*)(cA + r * 32 + ((quad ^ ((r >> 1) & 3)) * 8));
    }
    if (i + 2 < nk) stageA(i + 2);
    SCHED_FENCE();
    __builtin_amdgcn_s_barrier();
    asm volatile("s_waitcnt lgkmcnt(0)" ::: "memory");
    SCHED_FENCE();
    __builtin_amdgcn_s_setprio(1);
    #pragma unroll
    for (int mt = 0; mt < 2; ++mt)
      #pragma unroll
      for (int nt = 0; nt < 4; ++nt)
        acc[mt][nt] = __builtin_amdgcn_mfma_f32_16x16x32_bf16(af[mt], bfv[nt], acc[mt][nt], 0, 0, 0);
    __builtin_amdgcn_s_setprio(0);
    SCHED_FENCE();
    // phase 1: reads (af2/3) || stage B-half of tile i+2
    #pragma unroll
    for (int mt = 2; mt < 4; ++mt) {
      int r = waveM * 64 + mt * 16 + l16;
      af[mt] = *(const bf16x8*)(cA + r * 32 + ((quad ^ ((r >> 1) & 3)) * 8));
    }
    if (i + 2 < nk) stageB(i + 2);
    SCHED_FENCE();
    __builtin_amdgcn_s_barrier();
    asm volatile("s_waitcnt lgkmcnt(0)" ::: "memory");
    SCHED_FENCE();
    __builtin_amdgcn_s_setprio(1);
    #pragma unroll
    for (int mt = 2; mt < 4; ++mt)
      #pragma unroll
      for (int nt = 0; nt < 4; ++nt)
        acc[mt][nt] = __builtin_amdgcn_mfma_f32_16x16x32_bf16(af[mt], bfv[nt], acc[mt][nt], 0, 0, 0);
    __builtin_amdgcn_s_setprio(0);
    SCHED_FENCE();
  }

  const int wid = n0 >> 10;                  // 0:q 1:k 2:v 3:qb 4:kb
  const int cw0 = (n0 & 1023) + waveN * 64;  // head-aligned col within weight
  if (wid == 2) {
    // direct V^T store: vtbf[d_global][seq], acc rows are contiguous seq
    #pragma unroll
    for (int mt = 0; mt < 4; ++mt) {
      int row = m0 + waveM * 64 + mt * 16 + quad * 4;
      #pragma unroll
      for (int nt = 0; nt < 4; ++nt) {
        int col = cw0 + nt * 16 + l16;
        bf16x4 v;
        v[0] = (__bf16)acc[mt][nt][0]; v[1] = (__bf16)acc[mt][nt][1];
        v[2] = (__bf16)acc[mt][nt][2]; v[3] = (__bf16)acc[mt][nt][3];
        *(bf16x4*)(vtbf + (size_t)col * 2048 + row) = v;
      }
    }
  } else {
    const float inv0 = exp2f(-0.31143076f * (float)l16);
    const float inv1 = exp2f(-0.31143076f * (float)(16 + l16));
    #pragma unroll
    for (int mt = 0; mt < 4; ++mt) {
      #pragma unroll
      for (int r = 0; r < 4; ++r) {
        int srow = m0 + waveM * 64 + mt * 16 + quad * 4 + r;
        float a0 = acc[mt][0][r], a1 = acc[mt][1][r];
        float a2 = acc[mt][2][r], a3 = acc[mt][3][r];
        float ss = a0 * a0 + a1 * a1 + a2 * a2 + a3 * a3;
        ss += __shfl_xor(ss, 1); ss += __shfl_xor(ss, 2);
        ss += __shfl_xor(ss, 4); ss += __shfl_xor(ss, 8);
        float yn = 1.0f / fmaxf(sqrtf(ss), 1e-12f);
        float ang0 = (float)srow * inv0;
        float cb0 = (float)(__bf16)__cosf(ang0);
        float sb0 = (float)(__bf16)__sinf(ang0);
        float ang1 = (float)srow * inv1;
        float cb1 = (float)(__bf16)__cosf(ang1);
        float sb1 = (float)(__bf16)__sinf(ang1);
        float y0 = a0 * yn, y1 = a1 * yn, y2 = a2 * yn, y3 = a3 * yn;
        float o0 =  y0 * cb0 + y2 * sb0;   // d = l16
        float o1 =  y1 * cb1 + y3 * sb1;   // d = 16+l16
        float o2 = -y0 * sb0 + y2 * cb0;   // d = 32+l16
        float o3 = -y1 * sb1 + y3 * cb1;   // d = 48+l16
        size_t base = (size_t)srow * 1024 + cw0 + l16;
        if (wid == 0) {
          qbf[base]      = (__bf16)o0; qbf[base + 16] = (__bf16)o1;
          qbf[base + 32] = (__bf16)o2; qbf[base + 48] = (__bf16)o3;
        } else if (wid == 1) {
          kbf[base]      = (__bf16)o0; kbf[base + 16] = (__bf16)o1;
          kbf[base + 32] = (__bf16)o2; kbf[base + 48] = (__bf16)o3;
        } else if (wid == 3) {
          qb32[base]      = o0; qb32[base + 16] = o1;
          qb32[base + 32] = o2; qb32[base + 48] = o3;
        } else {
          kb32[base]      = o0; kb32[base + 16] = o1;
          kb32[base + 32] = o2; kb32[base + 48] = o3;
        }
      }
    }
  }
}

// ---------------- GEMM 128x128 ring-3, 2-phase, split-K partials ------------
__global__ __launch_bounds__(256, 3) void gemm_partk_k(
    const __bf16* __restrict__ A, const __bf16* __restrict__ Bt,
    float* __restrict__ P, int N, int K) {
  __shared__ __bf16 sA[3][128 * 32];
  __shared__ __bf16 sB[3][128 * 32];
  const int tid = threadIdx.x;
  const int lane = tid & 63;
  const int quad = lane >> 4, l16 = lane & 15;
  const int wave = tid >> 6;
  const int waveM = wave >> 1, waveN = wave & 1;
  const int m0 = blockIdx.y * 128, n0 = blockIdx.x * 128;
  const int kz = blockIdx.z, nz = gridDim.z;
  const int kper = K / nz, kbeg = kz * kper;
  const int nk = kper >> 5;
  const size_t MN = (size_t)gridDim.y * 128 * N;
  float* C = P + (size_t)kz * MN;
  const int rowS = tid >> 2;
  const int kg = ((tid & 3) ^ ((rowS >> 1) & 3)) * 8;
  const __bf16* gA0 = A + (size_t)(m0 + rowS) * K + kbeg + kg;
  const __bf16* gA1 = gA0 + (size_t)64 * K;
  const __bf16* gB0 = Bt + (size_t)(n0 + rowS) * K + kbeg + kg;
  const __bf16* gB1 = gB0 + (size_t)64 * K;
  const int lo0 = tid * 8, lo1 = 2048 + tid * 8;

  auto stageA = [&](int t) {
    __bf16* dA = sA[t % 3];
    GLD16(gA0 + t * 32, dA + lo0);
    GLD16(gA1 + t * 32, dA + lo1);
  };
  auto stageB = [&](int t) {
    __bf16* dB = sB[t % 3];
    GLD16(gB0 + t * 32, dB + lo0);
    GLD16(gB1 + t * 32, dB + lo1);
  };
  stageA(0); stageB(0);
  stageA(1); stageB(1);

  f32x4 acc[4][4] = {};
  #pragma unroll 1
  for (int i = 0; i < nk; ++i) {
    if (i < nk - 1)
      asm volatile("s_waitcnt vmcnt(4)" ::: "memory");
    else
      asm volatile("s_waitcnt vmcnt(0)" ::: "memory");
    __builtin_amdgcn_s_barrier();
    SCHED_FENCE();
    const __bf16* cA = sA[i % 3];
    const __bf16* cB = sB[i % 3];
    bf16x8 af[4], bfv[4];
    #pragma unroll
    for (int nt = 0; nt < 4; ++nt) {
      int r = waveN * 64 + nt * 16 + l16;
      bfv[nt] = *(const bf16x8*)(cB + r * 32 + ((quad ^ ((r >> 1) & 3)) * 8));
    }
    #pragma unroll
    for (int mt = 0; mt < 2; ++mt) {
      int r = waveM * 64 + mt * 16 + l16;
      af[mt] = *(const bf16x8*)(cA + r * 32 + ((quad ^ ((r >> 1) & 3)) * 8));
    }
    if (i + 2 < nk) stageA(i + 2);
    SCHED_FENCE();
    __builtin_amdgcn_s_barrier();
    asm volatile("s_waitcnt lgkmcnt(0)" ::: "memory");
    SCHED_FENCE();
    __builtin_amdgcn_s_setprio(1);
    #pragma unroll
    for (int mt = 0; mt < 2; ++mt)
      #pragma unroll
      for (int nt = 0; nt < 4; ++nt)
        acc[mt][nt] = __builtin_amdgcn_mfma_f32_16x16x32_bf16(af[mt], bfv[nt], acc[mt][nt], 0, 0, 0);
    __builtin_amdgcn_s_setprio(0);
    SCHED_FENCE();
    #pragma unroll
    for (int mt = 2; mt < 4; ++mt) {
      int r = waveM * 64 + mt * 16 + l16;
      af[mt] = *(const bf16x8*)(cA + r * 32 + ((quad ^ ((r >> 1) & 3)) * 8));
    }
    if (i + 2 < nk) stageB(i + 2);
    SCHED_FENCE();
    __builtin_amdgcn_s_barrier();
    asm volatile("s_waitcnt lgkmcnt(0)" ::: "memory");
    SCHED_FENCE();
    __builtin_amdgcn_s_setprio(1);
    #pragma unroll
    for (int mt = 2; mt < 4; ++mt)
      #pragma unroll
      for (int nt = 0; nt < 4; ++nt)
        acc[mt][nt] = __builtin_amdgcn_mfma_f32_16x16x32_bf16(af[mt], bfv[nt], acc[mt][nt], 0, 0, 0);
    __builtin_amdgcn_s_setprio(0);
    SCHED_FENCE();
  }
  #pragma unroll
  for (int mt = 0; mt < 4; ++mt) {
    int row = m0 + waveM * 64 + mt * 16 + quad * 4;
    #pragma unroll
    for (int nt = 0; nt < 4; ++nt) {
      int col = n0 + waveN * 64 + nt * 16 + l16;
      #pragma unroll
      for (int r = 0; r < 4; ++r)
        C[(size_t)(row + r) * N + col] = acc[mt][nt][r];
    }
  }
}

// ---------------- fused FFN1 + bias + SwiGLU, 256x256 ring-2, 2-phase -------
// Ring-2 (64 KiB LDS) -> 2 blocks/CU (was ring-4 @128 KiB, 1 block/CU):
// cross-block overlap now covers the phase-barrier waits. Per tile:
// vmcnt(0) [drains stage(t), issued a full tile earlier; nothing deeper in
// flight with ring-2 so counted==0] -> barrier [seal t-1 reads + all-waves-
// landed] -> stage(t+1) -> 2 phases {reads | bar | lgkmcnt(0) | 16 MFMA}.
__global__ __launch_bounds__(512, 2) void ffn1silu_k(
    const __bf16* __restrict__ A, const __bf16* __restrict__ W1t,
    const float* __restrict__ b1, __bf16* __restrict__ ffout) {
  __shared__ __bf16 sA[2][256 * 32];
  __shared__ __bf16 sB[2][256 * 32];
  const int tid = threadIdx.x, lane = tid & 63, w = tid >> 6;
  const int quad = lane >> 4, l16 = lane & 15;
  const int wm = w >> 2, wn = w & 3;          // 2 M-waves x 4 N-waves
  const int m0 = blockIdx.y * 256;            // M = 2048 -> 8
  const int n0p = blockIdx.x * 256;           // packed N = 8192 -> 32
  const int K = 1024, NKT = 32;
  const int rowS = tid >> 2;                  // 0..127
  const int kg = ((tid & 3) ^ ((rowS >> 1) & 3)) * 8;
  const __bf16* gA0 = A + (size_t)(m0 + rowS) * K + kg;
  const __bf16* gA1 = gA0 + (size_t)128 * K;
  const __bf16* gB0 = W1t + (size_t)(n0p + rowS) * K + kg;
  const __bf16* gB1 = gB0 + (size_t)128 * K;
  const int lo0 = tid * 8, lo1 = 4096 + tid * 8;

  f32x4 acc[8][4] = {};

  auto stageA = [&](int t) {
    __bf16* d = sA[t & 1];
    GLD16(gA0 + t * 32, d + lo0);
    GLD16(gA1 + t * 32, d + lo1);
  };
  auto stageB = [&](int t) {
    __bf16* d = sB[t & 1];
    GLD16(gB0 + t * 32, d + lo0);
    GLD16(gB1 + t * 32, d + lo1);
  };

  // prologue: prime tile 0
  stageA(0); stageB(0);

  #pragma unroll 1
  for (int t = 0; t < NKT; ++t) {
    asm volatile("s_waitcnt vmcnt(0)" ::: "memory");
    __builtin_amdgcn_s_barrier();     // seal t-1 reads + all waves' loads landed
    SCHED_FENCE();
    if (t + 1 < NKT) { stageA(t + 1); stageB(t + 1); }
    SCHED_FENCE();
    const __bf16* cA = sA[t & 1];
    const __bf16* cB = sB[t & 1];
    // phase 0: reads (bfr + af half0)
    bf16x8 bfr[4], af[4];
    #pragma unroll
    for (int nt = 0; nt < 4; ++nt) {
      int r = wn * 64 + nt * 16 + l16;
      bfr[nt] = *(const bf16x8*)(cB + r * 32 + ((quad ^ ((r >> 1) & 3)) * 8));
    }
    #pragma unroll
    for (int mt = 0; mt < 4; ++mt) {
      int r = wm * 128 + mt * 16 + l16;
      af[mt] = *(const bf16x8*)(cA + r * 32 + ((quad ^ ((r >> 1) & 3)) * 8));
    }
    SCHED_FENCE();
    __builtin_amdgcn_s_barrier();
    asm volatile("s_waitcnt lgkmcnt(0)" ::: "memory");
    SCHED_FENCE();
    __builtin_amdgcn_s_setprio(1);
    #pragma unroll
    for (int mt = 0; mt < 4; ++mt)
      #pragma unroll
      for (int nt = 0; nt < 4; ++nt)
        acc[mt][nt] = __builtin_amdgcn_mfma_f32_16x16x32_bf16(af[mt], bfr[nt], acc[mt][nt], 0, 0, 0);
    __builtin_amdgcn_s_setprio(0);
    SCHED_FENCE();
    // phase 1: reads (af half1)
    bf16x8 af1[4];
    #pragma unroll
    for (int mt = 0; mt < 4; ++mt) {
      int r = wm * 128 + 64 + mt * 16 + l16;
      af1[mt] = *(const bf16x8*)(cA + r * 32 + ((quad ^ ((r >> 1) & 3)) * 8));
    }
    SCHED_FENCE();
    __builtin_amdgcn_s_barrier();
    asm volatile("s_waitcnt lgkmcnt(0)" ::: "memory");
    SCHED_FENCE();
    __builtin_amdgcn_s_setprio(1);
    #pragma unroll
    for (int mt = 0; mt < 4; ++mt)
      #pragma unroll
      for (int nt = 0; nt < 4; ++nt)
        acc[4 + mt][nt] = __builtin_amdgcn_mfma_f32_16x16x32_bf16(af1[mt], bfr[nt], acc[4 + mt][nt], 0, 0, 0);
    __builtin_amdgcn_s_setprio(0);
    SCHED_FENCE();
  }

  // epilogue: bias + SwiGLU, unpack interleaved xp/gate
  const int colbase = (blockIdx.x * 4 + wn) * 32;   // logical col base (0..4095)
  #pragma unroll
  for (int j = 0; j < 8; ++j) {
    int row = m0 + wm * 128 + (j >> 2) * 64 + (j & 3) * 16 + quad * 4;
    #pragma unroll
    for (int p = 0; p < 2; ++p) {
      int col = colbase + p * 16 + l16;
      float bxv = b1[col], bgv = b1[col + 4096];
      #pragma unroll
      for (int r = 0; r < 4; ++r) {
        float xp = acc[j][p][r] + bxv;
        float g  = acc[j][p + 2][r] + bgv;
        float val = xp * g / (1.f + __expf(-g));
        ffout[(size_t)(row + r) * 5120 + 1024 + col] = (__bf16)val;
      }
    }
  }
}

// ---------------- combine: out = Σ4 partials + (bo+b2) + lam*h --------------
__global__ __launch_bounds__(256) void combine_k(
    const float* __restrict__ P, const float* __restrict__ b2,
    const float* __restrict__ bo, const float* __restrict__ hs,
    const float* __restrict__ plam, float* __restrict__ out) {
  const size_t MN = (size_t)2048 * 1024;
  size_t i = ((size_t)blockIdx.x * 256 + threadIdx.x) * 4;
  int col = (int)(i & 1023);
  float4 a0 = *(const float4*)(P + i);
  float4 a1 = *(const float4*)(P + MN + i);
  float4 a2 = *(const float4*)(P + 2 * MN + i);
  float4 a3 = *(const float4*)(P + 3 * MN + i);
  float4 h  = *(const float4*)(hs + i);
  float4 v2 = *(const float4*)(b2 + col);
  float4 vo = *(const float4*)(bo + col);
  float lam = plam[0];
  float4 o;
  o.x = (a0.x + a1.x) + (a2.x + a3.x) + v2.x + vo.x + lam * h.x;
  o.y = (a0.y + a1.y) + (a2.y + a3.y) + v2.y + vo.y + lam * h.y;
  o.z = (a0.z + a1.z) + (a2.z + a3.z) + v2.z + vo.z + lam * h.z;
  o.w = (a0.w + a1.w) + (a2.w + a3.w) + v2.w + vo.w + lam * h.w;
  *(float4*)(out + i) = o;
}

// ---------------- sb row-sum via two-level cumsum ---------------------------
__global__ __launch_bounds__(256) void kbsum_k(const float* __restrict__ kb,
                                               float* __restrict__ tsum,
                                               float* __restrict__ tsum8) {
  int t = blockIdx.x, h = blockIdx.y;
  int d = threadIdx.x & 63, w = threadIdx.x >> 6;
  size_t base = (size_t)h * 64 + d;
  float s = 0.f;
  #pragma unroll
  for (int r = 0; r < 8; ++r)
    s += kb[(size_t)(t * 32 + w * 8 + r) * 1024 + base];
  tsum8[(size_t)((t * 4 + w) * 16 + h) * 64 + d] = s;
  __shared__ float ps[4][64];
  ps[w][d] = s;
  __syncthreads();
  if (w == 0)
    tsum[(size_t)(t * 16 + h) * 64 + d] = (ps[0][d] + ps[1][d]) + (ps[2][d] + ps[3][d]);
}

__global__ __launch_bounds__(256) void sbrow2_k(const float* __restrict__ qb,
                                                const float* __restrict__ kb,
                                                const float* __restrict__ tsum,
                                                const float* __restrict__ tsum8,
                                                float* __restrict__ sb) {
  int t = blockIdx.x, h = blockIdx.y;
  int d = threadIdx.x & 63, g = threadIdx.x >> 6;
  size_t base = (size_t)h * 64 + d;
  float run = 0.f;
  for (int tp = 0; tp < t; ++tp) run += tsum[(size_t)(tp * 16 + h) * 64 + d];
  for (int w = 0; w < g; ++w) run += tsum8[(size_t)((t * 4 + w) * 16 + h) * 64 + d];
  int r0 = t * 32 + g * 8;
  for (int s0 = 0; s0 < 8; s0 += 4) {
    float p[4];
    #pragma unroll
    for (int u = 0; u < 4; ++u) {
      size_t off = (size_t)(r0 + s0 + u) * 1024 + base;
      run += kb[off];
      p[u] = qb[off] * run;
    }
    #pragma unroll
    for (int o = 32; o > 0; o >>= 1) {
      #pragma unroll
      for (int u = 0; u < 4; ++u) p[u] += __shfl_xor(p[u], o);
    }
    if (d == 0) {
      #pragma unroll
      for (int u = 0; u < 4; ++u) sb[(r0 + s0 + u) * 16 + h] = 0.125f * p[u];
    }
  }
}

// ---------------- flash attention: split-KV x4, fixed-max softmax -----------
__global__ __launch_bounds__(256) void attn_k(const __bf16* __restrict__ qg,
    const __bf16* __restrict__ kg, const __bf16* __restrict__ vtg,
    float* __restrict__ o_part, float* __restrict__ l_part) {
  __shared__ __bf16 sK[2][64 * 64];
  __shared__ __bf16 sVt[2][64 * 64];
  __shared__ __bf16 sP[4][16 * 64];
  const int pair = blockIdx.x, j4 = blockIdx.y, hh = blockIdx.z;
  const int tid = threadIdx.x, lane = tid & 63, w = tid >> 6;
  const int quad = lane >> 4, l16 = lane & 15;
  const int srow = tid >> 3;
  const int sg = (tid & 7) ^ (srow & 7);
  __bf16* sPw = sP[w];

  auto stage = [&](int kt) {
    int b = kt & 1;
    const __bf16* gK = kg + (size_t)(kt * 64 + srow) * 1024 + hh * 64 + sg * 8;
    const __bf16* gV = vtg + (size_t)(hh * 64 + srow) * 2048 + kt * 64 + sg * 8;
    GLD16(gK, sK[b] + tid * 8);
    GLD16(gK + (size_t)32 * 1024, sK[b] + tid * 8 + 2048);
    GLD16(gV, sVt[b] + tid * 8);
    GLD16(gV + (size_t)32 * 2048, sVt[b] + tid * 8 + 2048);
  };

  for (int phase = 0; phase < 2; ++phase) {
    const int qt = phase ? 31 - pair : pair;
    const int q0 = qt * 64;
    const int n = qt + 1;
    const int kb = (j4 * n) >> 2, ke = ((j4 + 1) * n) >> 2;
    bf16x8 qf[2];
    #pragma unroll
    for (int kk = 0; kk < 2; ++kk)
      qf[kk] = *(const bf16x8*)(qg + (size_t)(q0 + w * 16 + l16) * 1024 + hh * 64 + kk * 32 + quad * 8);
    f32x4 accO[4] = {};
    float l_[4] = {0.f, 0.f, 0.f, 0.f};   // lane-local partial sums

    __syncthreads();                 // seal previous phase's buffer reads
    if (kb < ke) stage(kb);

    for (int kt = kb; kt < ke; ++kt) {
      __syncthreads();               // implicit vmcnt(0): buf[kt&1] ready;
                                     // seals buf[(kt+1)&1] (last read kt-1)
      SCHED_FENCE();
      if (kt + 1 < ke) stage(kt + 1);
      SCHED_FENCE();
      const __bf16* cK = sK[kt & 1];
      const __bf16* cV = sVt[kt & 1];

      f32x4 s4[4];
      #pragma unroll
      for (int nt = 0; nt < 4; ++nt) {
        int r = nt * 16 + l16;
        bf16x8 b0 = *(const bf16x8*)(cK + r * 64 + ((quad ^ (r & 7)) * 8));
        bf16x8 b1 = *(const bf16x8*)(cK + r * 64 + (((4 + quad) ^ (r & 7)) * 8));
        f32x4 sa = {0.f, 0.f, 0.f, 0.f};
        sa = __builtin_amdgcn_mfma_f32_16x16x32_bf16(qf[0], b0, sa, 0, 0, 0);
        sa = __builtin_amdgcn_mfma_f32_16x16x32_bf16(qf[1], b1, sa, 0, 0, 0);
        s4[nt] = sa;
      }
      if (kt == qt) {
        #pragma unroll
        for (int nt = 0; nt < 4; ++nt)
          #pragma unroll
          for (int r = 0; r < 4; ++r)
            if (nt * 16 + l16 > w * 16 + quad * 4 + r) s4[nt][r] = -INFINITY;
      }
      // fixed-max softmax: p = exp(s - 1); accumulate l lane-locally
      float p[4][4];
      #pragma unroll
      for (int nt = 0; nt < 4; ++nt)
        #pragma unroll
        for (int r = 0; r < 4; ++r)
          p[nt][r] = __expf(s4[nt][r] - 1.0f);
      #pragma unroll
      for (int r = 0; r < 4; ++r)
        l_[r] += (p[0][r] + p[1][r]) + (p[2][r] + p[3][r]);
      #pragma unroll
      for (int nt = 0; nt < 4; ++nt)
        #pragma unroll
        for (int r = 0; r < 4; ++r) {
          int row = quad * 4 + r, col = nt * 16 + l16;
          sPw[row * 64 + (col ^ ((row & 7) << 3))] = (__bf16)p[nt][r];
        }
      #pragma unroll
      for (int kk = 0; kk < 2; ++kk) {
        bf16x8 a = *(const bf16x8*)(sPw + l16 * 64 + (((kk * 4 + quad) ^ (l16 & 7)) * 8));
        #pragma unroll
        for (int nt = 0; nt < 4; ++nt) {
          int vr = nt * 16 + l16;
          bf16x8 bv = *(const bf16x8*)(cV + vr * 64 + (((kk * 4 + quad) ^ (vr & 7)) * 8));
          accO[nt] = __builtin_amdgcn_mfma_f32_16x16x32_bf16(a, bv, accO[nt], 0, 0, 0);
        }
      }
      // no trailing barrier: sP is wave-private; K/V buffers are ring-2 sealed
    }
    // one 16-lane reduce of l per phase (was per tile)
    #pragma unroll
    for (int o = 1; o < 16; o <<= 1)
      #pragma unroll
      for (int r = 0; r < 4; ++r) l_[r] += __shfl_xor(l_[r], o);
    #pragma unroll
    for (int r = 0; r < 4; ++r) {
      int grow = q0 + w * 16 + quad * 4 + r;
      if (l16 == 0)
        l_part[((size_t)j4 * 2048 + grow) * 16 + hh] = l_[r];
      #pragma unroll
      for (int nt = 0; nt < 4; ++nt)
        o_part[((size_t)j4 * 2048 + grow) * 1024 + hh * 64 + nt * 16 + l16] = accO[nt][r];
    }
  }
}

// ---------------- merge 4 KV-partials -> y into concat (stride 5120) --------
__global__ __launch_bounds__(256) void attnmerge_k(const float* __restrict__ o_part,
    const float* __restrict__ l_part, const float* __restrict__ sbr,
    const float* __restrict__ pl2s, __bf16* __restrict__ yo) {
  int idx = blockIdx.x * 256 + threadIdx.x;
  int s = idx >> 8, rem = idx & 255;
  int h = rem >> 4, dg = (rem & 15) * 4;
  float den = 0.f;
  float4 acc = {0.f, 0.f, 0.f, 0.f};
  #pragma unroll
  for (int j = 0; j < 4; ++j) {
    den += l_part[((size_t)j * 2048 + s) * 16 + h];
    float4 o = *(const float4*)(o_part + ((size_t)j * 2048 + s) * 1024 + h * 64 + dg);
    acc.x += o.x; acc.y += o.y; acc.z += o.z; acc.w += o.w;
  }
  float sc = pl2s[0] / den;
  float add = sbr[s * 16 + h];
  __bf16* yp = yo + (size_t)s * 5120 + h * 64 + dg;
  yp[0] = (__bf16)(sc * acc.x + add);
  yp[1] = (__bf16)(sc * acc.y + add);
  yp[2] = (__bf16)(sc * acc.z + add);
  yp[3] = (__bf16)(sc * acc.w + add);
}

extern "C" void kernel_launch(void* const* d_in, const int* in_sizes, int n_in,
                              void* d_out, int out_size, void* d_ws, size_t ws_size,
                              hipStream_t stream) {
  (void)in_sizes; (void)n_in; (void)out_size; (void)ws_size;
  const float* hs   = (const float*)d_in[0];
  const float* Wq   = (const float*)d_in[1];
  const float* Wk   = (const float*)d_in[2];
  const float* Wv   = (const float*)d_in[3];
  const float* Wqb  = (const float*)d_in[4];
  const float* Wkb  = (const float*)d_in[5];
  const float* Wo   = (const float*)d_in[6];
  const float* bo   = (const float*)d_in[7];
  const float* W1   = (const float*)d_in[8];
  const float* b1   = (const float*)d_in[9];
  const float* W2   = (const float*)d_in[10];
  const float* b2   = (const float*)d_in[11];
  const float* plam = (const float*)d_in[12];
  const float* pl2s = (const float*)d_in[13];
  float* out = (float*)d_out;
  char* ws = (char*)d_ws;

  size_t off = 0;
  auto alloc = [&](size_t bytes) { char* p = ws + off; off += (bytes + 255) & ~(size_t)255; return p; };
  __bf16* Wt5    = (__bf16*)alloc((size_t)5 * 1024 * 1024 * 2);
  __bf16* WoW2t  = (__bf16*)alloc((size_t)1024 * 5120 * 2);   // [n][k], k: Wo 0..1023, W2 1024..5119
  __bf16* W1t    = (__bf16*)alloc((size_t)8192 * 1024 * 2);   // packed xp/gate 32-col interleave
  __bf16* xbf    = (__bf16*)alloc((size_t)2048 * 1024 * 2);
  __bf16* concat = (__bf16*)alloc((size_t)2048 * 5120 * 2);   // [y | ffin] bf16
  float*  proj  = (float*)alloc((size_t)2048 * 5120 * 4);     // o_part / gpart scratch
  float*  qbf32 = (float*)alloc((size_t)2048 * 1024 * 4);
  float*  kbf32 = (float*)alloc((size_t)2048 * 1024 * 4);
  __bf16* qbf   = (__bf16*)alloc((size_t)2048 * 1024 * 2);
  __bf16* kbf   = (__bf16*)alloc((size_t)2048 * 1024 * 2);
  float*  o_part = proj;                                      // 4 x 8 MB
  float*  l_part = qbf32;                                     // 512 KB (after sbrow2)
  float*  gpart  = proj;                                      // 4 x 8 MB (after attnmerge)
  __bf16* vtbf  = (__bf16*)alloc((size_t)1024 * 2048 * 2);
  float*  sbrow = (float*)alloc((size_t)2048 * 16 * 4);
  float*  tsum  = (float*)alloc((size_t)64 * 16 * 64 * 4);
  float*  tsum8 = (float*)alloc((size_t)256 * 16 * 64 * 4);

  // merged weight repack
  repack_k<<<18432, 256, 0, stream>>>(Wq, Wk, Wv, Wqb, Wkb, Wo, W2, W1,
                                      Wt5, WoW2t, W1t);

  rmsnorm_k<<<2048, 256, 0, stream>>>(hs, xbf);
  // QKV GEMM: fused l2norm+RoPE epilogue + direct V^T store
  gemm_qkv_k<<<dim3(40, 16), 256, 0, stream>>>(xbf, Wt5, qbf, kbf,
                                               qbf32, kbf32, vtbf);
  kbsum_k<<<dim3(64, 16), 256, 0, stream>>>(kbf32, tsum, tsum8);
  sbrow2_k<<<dim3(64, 16), 256, 0, stream>>>(qbf32, kbf32, tsum, tsum8, sbrow);
  attn_k<<<dim3(16, 4, 16), 256, 0, stream>>>(qbf, kbf, vtbf, o_part, l_part);
  attnmerge_k<<<2048, 256, 0, stream>>>(o_part, l_part, sbrow, pl2s, concat);
  // fused FFN1 + bias + SwiGLU -> concat cols 1024..5119 (256x256 ring-2, 2-phase)
  ffn1silu_k<<<dim3(32, 8), 512, 0, stream>>>(xbf, W1t, b1, concat);
  // merged (Wo + FFN2): [y|ffin] @ [Wo;W2], K=5120, split-K x4 -> partials
  gemm_partk_k<<<dim3(8, 16, 4), 256, 0, stream>>>(concat, WoW2t, gpart, 1024, 5120);
  // out = Σ partials + (bo+b2) + lam*h
  combine_k<<<2048, 256, 0, stream>>>(gpart, b2, bo, hs, plam, out);
}

// Round 11
// 326.975 us; speedup vs baseline: 1.0314x; 1.0314x over previous
//
#include <hip/hip_runtime.h>
#include <hip/hip_bf16.h>
#include <math.h>

typedef __bf16 bf16x8 __attribute__((ext_vector_type(8)));
typedef __bf16 bf16x4 __attribute__((ext_vector_type(4)));
typedef float  f32x4  __attribute__((ext_vector_type(4)));

#define GLD16(g, l) __builtin_amdgcn_global_load_lds(                      \
    (const __attribute__((address_space(1))) void*)(g),                    \
    (__attribute__((address_space(3))) void*)(l), 16, 0, 0)

#define SCHED_FENCE() __builtin_amdgcn_sched_barrier(0)

// BK=32 LDS tiles (64 B rows): global k-group g of row r stored at slot
// g ^ ((r>>1)&3) -> all ds_read_b128 fragment reads are 2-way (free).

// ---------------- merged weight repack (was 3 kernels) ----------------------
__global__ __launch_bounds__(256) void repack_k(
    const float* __restrict__ Wq, const float* __restrict__ Wk,
    const float* __restrict__ Wv, const float* __restrict__ Wqb,
    const float* __restrict__ Wkb, const float* __restrict__ Wo,
    const float* __restrict__ W2, const float* __restrict__ W1,
    __bf16* __restrict__ Wt5, __bf16* __restrict__ WoW2t,
    __bf16* __restrict__ W1t) {
  int t = blockIdx.x;
  const float* in; __bf16* outp;
  int ldin, ldout, r0, c0, cin0, oofs;
  if (t < 5120) {
    int w = t >> 10, rem = t & 1023;
    const float* src[5] = {Wq, Wk, Wv, Wqb, Wkb};
    in = src[w]; ldin = 1024;
    r0 = (rem >> 5) << 5; c0 = (rem & 31) << 5; cin0 = c0;
    outp = Wt5 + (size_t)w * 1048576; ldout = 1024; oofs = 0;
  } else if (t < 6144) {
    int rem = t - 5120;
    in = Wo; ldin = 1024;
    r0 = (rem >> 5) << 5; c0 = (rem & 31) << 5; cin0 = c0;
    outp = WoW2t; ldout = 5120; oofs = 0;
  } else if (t < 10240) {
    int rem = t - 6144;
    in = W2; ldin = 1024;
    r0 = (rem >> 5) << 5; c0 = (rem & 31) << 5; cin0 = c0;
    outp = WoW2t; ldout = 5120; oofs = 1024;
  } else {
    int rem = t - 10240;
    in = W1; ldin = 8192;
    c0 = (rem & 255) << 5; r0 = (rem >> 8) << 5;
    cin0 = ((c0 >> 5) & 1) * 4096 + (c0 >> 6) * 32;
    outp = W1t; ldout = 1024; oofs = 0;
  }
  __shared__ float sh[32][33];
  int tid = threadIdx.x, tx = tid & 31, ty = tid >> 5;
  #pragma unroll
  for (int i = ty; i < 32; i += 8)
    sh[i][tx] = in[(size_t)(r0 + i) * ldin + cin0 + tx];
  __syncthreads();
  #pragma unroll
  for (int i = ty; i < 32; i += 8)
    outp[(size_t)(c0 + i) * ldout + oofs + r0 + tx] = (__bf16)sh[tx][i];
}

// ---------------- RMSNorm ---------------------------------------------------
__global__ __launch_bounds__(256) void rmsnorm_k(const float* __restrict__ hs,
                                                 __bf16* __restrict__ x) {
  int row = blockIdx.x, tid = threadIdx.x;
  const float4 v = ((const float4*)(hs + (size_t)row * 1024))[tid];
  float ss = v.x * v.x + v.y * v.y + v.z * v.z + v.w * v.w;
  #pragma unroll
  for (int o = 32; o > 0; o >>= 1) ss += __shfl_xor(ss, o);
  __shared__ float ps[4];
  if ((tid & 63) == 0) ps[tid >> 6] = ss;
  __syncthreads();
  float tot = ps[0] + ps[1] + ps[2] + ps[3];
  float r = rsqrtf(tot * (1.0f / 1024.0f) + 1.1920929e-7f);
  __bf16* xr = x + (size_t)row * 1024 + tid * 4;
  xr[0] = (__bf16)(v.x * r); xr[1] = (__bf16)(v.y * r);
  xr[2] = (__bf16)(v.z * r); xr[3] = (__bf16)(v.w * r);
}

// ---------------- GEMM 128x128 ring-3, 2-phase, fused l2norm/RoPE -----------
__global__ __launch_bounds__(256, 3) void gemm_qkv_k(
    const __bf16* __restrict__ A, const __bf16* __restrict__ Bt,
    __bf16* __restrict__ qbf, __bf16* __restrict__ kbf,
    float* __restrict__ qb32, float* __restrict__ kb32,
    __bf16* __restrict__ vtbf) {
  const int K = 1024;
  __shared__ __bf16 sA[3][128 * 32];
  __shared__ __bf16 sB[3][128 * 32];
  const int tid = threadIdx.x;
  const int lane = tid & 63;
  const int quad = lane >> 4, l16 = lane & 15;
  const int wave = tid >> 6;
  const int waveM = wave >> 1, waveN = wave & 1;
  const int m0 = blockIdx.y * 128, n0 = blockIdx.x * 128;
  const int nk = K >> 5;
  const int rowS = tid >> 2;
  const int kg = ((tid & 3) ^ ((rowS >> 1) & 3)) * 8;
  const __bf16* gA0 = A + (size_t)(m0 + rowS) * K + kg;
  const __bf16* gA1 = gA0 + (size_t)64 * K;
  const __bf16* gB0 = Bt + (size_t)(n0 + rowS) * K + kg;
  const __bf16* gB1 = gB0 + (size_t)64 * K;
  const int lo0 = tid * 8, lo1 = 2048 + tid * 8;

  auto stageA = [&](int t) {
    __bf16* dA = sA[t % 3];
    GLD16(gA0 + t * 32, dA + lo0);
    GLD16(gA1 + t * 32, dA + lo1);
  };
  auto stageB = [&](int t) {
    __bf16* dB = sB[t % 3];
    GLD16(gB0 + t * 32, dB + lo0);
    GLD16(gB1 + t * 32, dB + lo1);
  };
  stageA(0); stageB(0);
  stageA(1); stageB(1);

  f32x4 acc[4][4] = {};
  #pragma unroll 1
  for (int i = 0; i < nk; ++i) {
    if (i < nk - 1)
      asm volatile("s_waitcnt vmcnt(4)" ::: "memory");
    else
      asm volatile("s_waitcnt vmcnt(0)" ::: "memory");
    __builtin_amdgcn_s_barrier();
    SCHED_FENCE();
    const __bf16* cA = sA[i % 3];
    const __bf16* cB = sB[i % 3];
    // phase 0: reads (bfv + af0/1) || stage A-half of tile i+2
    bf16x8 af[4], bfv[4];
    #pragma unroll
    for (int nt = 0; nt < 4; ++nt) {
      int r = waveN * 64 + nt * 16 + l16;
      bfv[nt] = *(const bf16x8*)(cB + r * 32 + ((quad ^ ((r >> 1) & 3)) * 8));
    }
    #pragma unroll
    for (int mt = 0; mt < 2; ++mt) {
      int r = waveM * 64 + mt * 16 + l16;
      af[mt] = *(const bf16x8*)(cA + r * 32 + ((quad ^ ((r >> 1) & 3)) * 8));
    }
    if (i + 2 < nk) stageA(i + 2);
    SCHED_FENCE();
    __builtin_amdgcn_s_barrier();
    asm volatile("s_waitcnt lgkmcnt(0)" ::: "memory");
    SCHED_FENCE();
    __builtin_amdgcn_s_setprio(1);
    #pragma unroll
    for (int mt = 0; mt < 2; ++mt)
      #pragma unroll
      for (int nt = 0; nt < 4; ++nt)
        acc[mt][nt] = __builtin_amdgcn_mfma_f32_16x16x32_bf16(af[mt], bfv[nt], acc[mt][nt], 0, 0, 0);
    __builtin_amdgcn_s_setprio(0);
    SCHED_FENCE();
    // phase 1: reads (af2/3) || stage B-half of tile i+2
    #pragma unroll
    for (int mt = 2; mt < 4; ++mt) {
      int r = waveM * 64 + mt * 16 + l16;
      af[mt] = *(const bf16x8*)(cA + r * 32 + ((quad ^ ((r >> 1) & 3)) * 8));
    }
    if (i + 2 < nk) stageB(i + 2);
    SCHED_FENCE();
    __builtin_amdgcn_s_barrier();
    asm volatile("s_waitcnt lgkmcnt(0)" ::: "memory");
    SCHED_FENCE();
    __builtin_amdgcn_s_setprio(1);
    #pragma unroll
    for (int mt = 2; mt < 4; ++mt)
      #pragma unroll
      for (int nt = 0; nt < 4; ++nt)
        acc[mt][nt] = __builtin_amdgcn_mfma_f32_16x16x32_bf16(af[mt], bfv[nt], acc[mt][nt], 0, 0, 0);
    __builtin_amdgcn_s_setprio(0);
    SCHED_FENCE();
  }

  const int wid = n0 >> 10;                  // 0:q 1:k 2:v 3:qb 4:kb
  const int cw0 = (n0 & 1023) + waveN * 64;  // head-aligned col within weight
  if (wid == 2) {
    // direct V^T store: vtbf[d_global][seq], acc rows are contiguous seq
    #pragma unroll
    for (int mt = 0; mt < 4; ++mt) {
      int row = m0 + waveM * 64 + mt * 16 + quad * 4;
      #pragma unroll
      for (int nt = 0; nt < 4; ++nt) {
        int col = cw0 + nt * 16 + l16;
        bf16x4 v;
        v[0] = (__bf16)acc[mt][nt][0]; v[1] = (__bf16)acc[mt][nt][1];
        v[2] = (__bf16)acc[mt][nt][2]; v[3] = (__bf16)acc[mt][nt][3];
        *(bf16x4*)(vtbf + (size_t)col * 2048 + row) = v;
      }
    }
  } else {
    const float inv0 = exp2f(-0.31143076f * (float)l16);
    const float inv1 = exp2f(-0.31143076f * (float)(16 + l16));
    #pragma unroll
    for (int mt = 0; mt < 4; ++mt) {
      #pragma unroll
      for (int r = 0; r < 4; ++r) {
        int srow = m0 + waveM * 64 + mt * 16 + quad * 4 + r;
        float a0 = acc[mt][0][r], a1 = acc[mt][1][r];
        float a2 = acc[mt][2][r], a3 = acc[mt][3][r];
        float ss = a0 * a0 + a1 * a1 + a2 * a2 + a3 * a3;
        ss += __shfl_xor(ss, 1); ss += __shfl_xor(ss, 2);
        ss += __shfl_xor(ss, 4); ss += __shfl_xor(ss, 8);
        float yn = 1.0f / fmaxf(sqrtf(ss), 1e-12f);
        float ang0 = (float)srow * inv0;
        float cb0 = (float)(__bf16)__cosf(ang0);
        float sb0 = (float)(__bf16)__sinf(ang0);
        float ang1 = (float)srow * inv1;
        float cb1 = (float)(__bf16)__cosf(ang1);
        float sb1 = (float)(__bf16)__sinf(ang1);
        float y0 = a0 * yn, y1 = a1 * yn, y2 = a2 * yn, y3 = a3 * yn;
        float o0 =  y0 * cb0 + y2 * sb0;   // d = l16
        float o1 =  y1 * cb1 + y3 * sb1;   // d = 16+l16
        float o2 = -y0 * sb0 + y2 * cb0;   // d = 32+l16
        float o3 = -y1 * sb1 + y3 * cb1;   // d = 48+l16
        size_t base = (size_t)srow * 1024 + cw0 + l16;
        if (wid == 0) {
          qbf[base]      = (__bf16)o0; qbf[base + 16] = (__bf16)o1;
          qbf[base + 32] = (__bf16)o2; qbf[base + 48] = (__bf16)o3;
        } else if (wid == 1) {
          kbf[base]      = (__bf16)o0; kbf[base + 16] = (__bf16)o1;
          kbf[base + 32] = (__bf16)o2; kbf[base + 48] = (__bf16)o3;
        } else if (wid == 3) {
          qb32[base]      = o0; qb32[base + 16] = o1;
          qb32[base + 32] = o2; qb32[base + 48] = o3;
        } else {
          kb32[base]      = o0; kb32[base + 16] = o1;
          kb32[base + 32] = o2; kb32[base + 48] = o3;
        }
      }
    }
  }
}

// ---------------- GEMM 128x128 ring-3, 2-phase, split-K partials ------------
__global__ __launch_bounds__(256, 3) void gemm_partk_k(
    const __bf16* __restrict__ A, const __bf16* __restrict__ Bt,
    float* __restrict__ P, int N, int K) {
  __shared__ __bf16 sA[3][128 * 32];
  __shared__ __bf16 sB[3][128 * 32];
  const int tid = threadIdx.x;
  const int lane = tid & 63;
  const int quad = lane >> 4, l16 = lane & 15;
  const int wave = tid >> 6;
  const int waveM = wave >> 1, waveN = wave & 1;
  const int m0 = blockIdx.y * 128, n0 = blockIdx.x * 128;
  const int kz = blockIdx.z, nz = gridDim.z;
  const int kper = K / nz, kbeg = kz * kper;
  const int nk = kper >> 5;
  const size_t MN = (size_t)gridDim.y * 128 * N;
  float* C = P + (size_t)kz * MN;
  const int rowS = tid >> 2;
  const int kg = ((tid & 3) ^ ((rowS >> 1) & 3)) * 8;
  const __bf16* gA0 = A + (size_t)(m0 + rowS) * K + kbeg + kg;
  const __bf16* gA1 = gA0 + (size_t)64 * K;
  const __bf16* gB0 = Bt + (size_t)(n0 + rowS) * K + kbeg + kg;
  const __bf16* gB1 = gB0 + (size_t)64 * K;
  const int lo0 = tid * 8, lo1 = 2048 + tid * 8;

  auto stageA = [&](int t) {
    __bf16* dA = sA[t % 3];
    GLD16(gA0 + t * 32, dA + lo0);
    GLD16(gA1 + t * 32, dA + lo1);
  };
  auto stageB = [&](int t) {
    __bf16* dB = sB[t % 3];
    GLD16(gB0 + t * 32, dB + lo0);
    GLD16(gB1 + t * 32, dB + lo1);
  };
  stageA(0); stageB(0);
  stageA(1); stageB(1);

  f32x4 acc[4][4] = {};
  #pragma unroll 1
  for (int i = 0; i < nk; ++i) {
    if (i < nk - 1)
      asm volatile("s_waitcnt vmcnt(4)" ::: "memory");
    else
      asm volatile("s_waitcnt vmcnt(0)" ::: "memory");
    __builtin_amdgcn_s_barrier();
    SCHED_FENCE();
    const __bf16* cA = sA[i % 3];
    const __bf16* cB = sB[i % 3];
    bf16x8 af[4], bfv[4];
    #pragma unroll
    for (int nt = 0; nt < 4; ++nt) {
      int r = waveN * 64 + nt * 16 + l16;
      bfv[nt] = *(const bf16x8*)(cB + r * 32 + ((quad ^ ((r >> 1) & 3)) * 8));
    }
    #pragma unroll
    for (int mt = 0; mt < 2; ++mt) {
      int r = waveM * 64 + mt * 16 + l16;
      af[mt] = *(const bf16x8*)(cA + r * 32 + ((quad ^ ((r >> 1) & 3)) * 8));
    }
    if (i + 2 < nk) stageA(i + 2);
    SCHED_FENCE();
    __builtin_amdgcn_s_barrier();
    asm volatile("s_waitcnt lgkmcnt(0)" ::: "memory");
    SCHED_FENCE();
    __builtin_amdgcn_s_setprio(1);
    #pragma unroll
    for (int mt = 0; mt < 2; ++mt)
      #pragma unroll
      for (int nt = 0; nt < 4; ++nt)
        acc[mt][nt] = __builtin_amdgcn_mfma_f32_16x16x32_bf16(af[mt], bfv[nt], acc[mt][nt], 0, 0, 0);
    __builtin_amdgcn_s_setprio(0);
    SCHED_FENCE();
    #pragma unroll
    for (int mt = 2; mt < 4; ++mt) {
      int r = waveM * 64 + mt * 16 + l16;
      af[mt] = *(const bf16x8*)(cA + r * 32 + ((quad ^ ((r >> 1) & 3)) * 8));
    }
    if (i + 2 < nk) stageB(i + 2);
    SCHED_FENCE();
    __builtin_amdgcn_s_barrier();
    asm volatile("s_waitcnt lgkmcnt(0)" ::: "memory");
    SCHED_FENCE();
    __builtin_amdgcn_s_setprio(1);
    #pragma unroll
    for (int mt = 2; mt < 4; ++mt)
      #pragma unroll
      for (int nt = 0; nt < 4; ++nt)
        acc[mt][nt] = __builtin_amdgcn_mfma_f32_16x16x32_bf16(af[mt], bfv[nt], acc[mt][nt], 0, 0, 0);
    __builtin_amdgcn_s_setprio(0);
    SCHED_FENCE();
  }
  #pragma unroll
  for (int mt = 0; mt < 4; ++mt) {
    int row = m0 + waveM * 64 + mt * 16 + quad * 4;
    #pragma unroll
    for (int nt = 0; nt < 4; ++nt) {
      int col = n0 + waveN * 64 + nt * 16 + l16;
      #pragma unroll
      for (int r = 0; r < 4; ++r)
        C[(size_t)(row + r) * N + col] = acc[mt][nt][r];
    }
  }
}

// ---------------- fused FFN1 + bias + SwiGLU, 256x256 ring-4, 2-phase -------
// REVERTED to round-9 (verified 42.8 us). Ring-2 experiment (round 10)
// regressed to 55.7: grid is 256 blocks = exactly 1/CU, so halving LDS
// cannot raise residency — it only collapsed the 3-tile prefetch lead.
// 1 block/CU is structural at the 256^2 tile; pipeline depth is the lever.
__global__ __launch_bounds__(512, 2) void ffn1silu_k(
    const __bf16* __restrict__ A, const __bf16* __restrict__ W1t,
    const float* __restrict__ b1, __bf16* __restrict__ ffout) {
  __shared__ __bf16 sA[4][256 * 32];
  __shared__ __bf16 sB[4][256 * 32];
  const int tid = threadIdx.x, lane = tid & 63, w = tid >> 6;
  const int quad = lane >> 4, l16 = lane & 15;
  const int wm = w >> 2, wn = w & 3;          // 2 M-waves x 4 N-waves
  const int m0 = blockIdx.y * 256;            // M = 2048 -> 8
  const int n0p = blockIdx.x * 256;           // packed N = 8192 -> 32
  const int K = 1024, NKT = 32;
  const int rowS = tid >> 2;                  // 0..127
  const int kg = ((tid & 3) ^ ((rowS >> 1) & 3)) * 8;
  const __bf16* gA0 = A + (size_t)(m0 + rowS) * K + kg;
  const __bf16* gA1 = gA0 + (size_t)128 * K;
  const __bf16* gB0 = W1t + (size_t)(n0p + rowS) * K + kg;
  const __bf16* gB1 = gB0 + (size_t)128 * K;
  const int lo0 = tid * 8, lo1 = 4096 + tid * 8;

  f32x4 acc[8][4] = {};

  auto stageA = [&](int t) {
    __bf16* d = sA[t & 3];
    GLD16(gA0 + t * 32, d + lo0);
    GLD16(gA1 + t * 32, d + lo1);
  };
  auto stageB = [&](int t) {
    __bf16* d = sB[t & 3];
    GLD16(gB0 + t * 32, d + lo0);
    GLD16(gB1 + t * 32, d + lo1);
  };

  // prologue: prime tiles 0,1,2 (12 loads in flight)
  stageA(0); stageB(0);
  stageA(1); stageB(1);
  stageA(2); stageB(2);

  #pragma unroll 1
  for (int t = 0; t < NKT; ++t) {
    if (t < NKT - 2)
      asm volatile("s_waitcnt vmcnt(8)" ::: "memory");
    else if (t == NKT - 2)
      asm volatile("s_waitcnt vmcnt(4)" ::: "memory");
    else
      asm volatile("s_waitcnt vmcnt(0)" ::: "memory");
    __builtin_amdgcn_s_barrier();
    SCHED_FENCE();
    const __bf16* cA = sA[t & 3];
    const __bf16* cB = sB[t & 3];
    // phase 0: reads (bfr + af half0) || stageA(t+3)
    bf16x8 bfr[4], af[4];
    #pragma unroll
    for (int nt = 0; nt < 4; ++nt) {
      int r = wn * 64 + nt * 16 + l16;
      bfr[nt] = *(const bf16x8*)(cB + r * 32 + ((quad ^ ((r >> 1) & 3)) * 8));
    }
    #pragma unroll
    for (int mt = 0; mt < 4; ++mt) {
      int r = wm * 128 + mt * 16 + l16;
      af[mt] = *(const bf16x8*)(cA + r * 32 + ((quad ^ ((r >> 1) & 3)) * 8));
    }
    if (t + 3 < NKT) stageA(t + 3);
    SCHED_FENCE();
    __builtin_amdgcn_s_barrier();
    asm volatile("s_waitcnt lgkmcnt(0)" ::: "memory");
    SCHED_FENCE();
    __builtin_amdgcn_s_setprio(1);
    #pragma unroll
    for (int mt = 0; mt < 4; ++mt)
      #pragma unroll
      for (int nt = 0; nt < 4; ++nt)
        acc[mt][nt] = __builtin_amdgcn_mfma_f32_16x16x32_bf16(af[mt], bfr[nt], acc[mt][nt], 0, 0, 0);
    __builtin_amdgcn_s_setprio(0);
    SCHED_FENCE();
    // phase 1: reads (af half1) || stageB(t+3)
    bf16x8 af1[4];
    #pragma unroll
    for (int mt = 0; mt < 4; ++mt) {
      int r = wm * 128 + 64 + mt * 16 + l16;
      af1[mt] = *(const bf16x8*)(cA + r * 32 + ((quad ^ ((r >> 1) & 3)) * 8));
    }
    if (t + 3 < NKT) stageB(t + 3);
    SCHED_FENCE();
    __builtin_amdgcn_s_barrier();
    asm volatile("s_waitcnt lgkmcnt(0)" ::: "memory");
    SCHED_FENCE();
    __builtin_amdgcn_s_setprio(1);
    #pragma unroll
    for (int mt = 0; mt < 4; ++mt)
      #pragma unroll
      for (int nt = 0; nt < 4; ++nt)
        acc[4 + mt][nt] = __builtin_amdgcn_mfma_f32_16x16x32_bf16(af1[mt], bfr[nt], acc[4 + mt][nt], 0, 0, 0);
    __builtin_amdgcn_s_setprio(0);
    SCHED_FENCE();
  }

  // epilogue: bias + SwiGLU, unpack interleaved xp/gate
  const int colbase = (blockIdx.x * 4 + wn) * 32;   // logical col base (0..4095)
  #pragma unroll
  for (int j = 0; j < 8; ++j) {
    int row = m0 + wm * 128 + (j >> 2) * 64 + (j & 3) * 16 + quad * 4;
    #pragma unroll
    for (int p = 0; p < 2; ++p) {
      int col = colbase + p * 16 + l16;
      float bxv = b1[col], bgv = b1[col + 4096];
      #pragma unroll
      for (int r = 0; r < 4; ++r) {
        float xp = acc[j][p][r] + bxv;
        float g  = acc[j][p + 2][r] + bgv;
        float val = xp * g / (1.f + __expf(-g));
        ffout[(size_t)(row + r) * 5120 + 1024 + col] = (__bf16)val;
      }
    }
  }
}

// ---------------- combine: out = Σ4 partials + (bo+b2) + lam*h --------------
__global__ __launch_bounds__(256) void combine_k(
    const float* __restrict__ P, const float* __restrict__ b2,
    const float* __restrict__ bo, const float* __restrict__ hs,
    const float* __restrict__ plam, float* __restrict__ out) {
  const size_t MN = (size_t)2048 * 1024;
  size_t i = ((size_t)blockIdx.x * 256 + threadIdx.x) * 4;
  int col = (int)(i & 1023);
  float4 a0 = *(const float4*)(P + i);
  float4 a1 = *(const float4*)(P + MN + i);
  float4 a2 = *(const float4*)(P + 2 * MN + i);
  float4 a3 = *(const float4*)(P + 3 * MN + i);
  float4 h  = *(const float4*)(hs + i);
  float4 v2 = *(const float4*)(b2 + col);
  float4 vo = *(const float4*)(bo + col);
  float lam = plam[0];
  float4 o;
  o.x = (a0.x + a1.x) + (a2.x + a3.x) + v2.x + vo.x + lam * h.x;
  o.y = (a0.y + a1.y) + (a2.y + a3.y) + v2.y + vo.y + lam * h.y;
  o.z = (a0.z + a1.z) + (a2.z + a3.z) + v2.z + vo.z + lam * h.z;
  o.w = (a0.w + a1.w) + (a2.w + a3.w) + v2.w + vo.w + lam * h.w;
  *(float4*)(out + i) = o;
}

// ---------------- sb row-sum via two-level cumsum ---------------------------
__global__ __launch_bounds__(256) void kbsum_k(const float* __restrict__ kb,
                                               float* __restrict__ tsum,
                                               float* __restrict__ tsum8) {
  int t = blockIdx.x, h = blockIdx.y;
  int d = threadIdx.x & 63, w = threadIdx.x >> 6;
  size_t base = (size_t)h * 64 + d;
  float s = 0.f;
  #pragma unroll
  for (int r = 0; r < 8; ++r)
    s += kb[(size_t)(t * 32 + w * 8 + r) * 1024 + base];
  tsum8[(size_t)((t * 4 + w) * 16 + h) * 64 + d] = s;
  __shared__ float ps[4][64];
  ps[w][d] = s;
  __syncthreads();
  if (w == 0)
    tsum[(size_t)(t * 16 + h) * 64 + d] = (ps[0][d] + ps[1][d]) + (ps[2][d] + ps[3][d]);
}

__global__ __launch_bounds__(256) void sbrow2_k(const float* __restrict__ qb,
                                                const float* __restrict__ kb,
                                                const float* __restrict__ tsum,
                                                const float* __restrict__ tsum8,
                                                float* __restrict__ sb) {
  int t = blockIdx.x, h = blockIdx.y;
  int d = threadIdx.x & 63, g = threadIdx.x >> 6;
  size_t base = (size_t)h * 64 + d;
  float run = 0.f;
  for (int tp = 0; tp < t; ++tp) run += tsum[(size_t)(tp * 16 + h) * 64 + d];
  for (int w = 0; w < g; ++w) run += tsum8[(size_t)((t * 4 + w) * 16 + h) * 64 + d];
  int r0 = t * 32 + g * 8;
  for (int s0 = 0; s0 < 8; s0 += 4) {
    float p[4];
    #pragma unroll
    for (int u = 0; u < 4; ++u) {
      size_t off = (size_t)(r0 + s0 + u) * 1024 + base;
      run += kb[off];
      p[u] = qb[off] * run;
    }
    #pragma unroll
    for (int o = 32; o > 0; o >>= 1) {
      #pragma unroll
      for (int u = 0; u < 4; ++u) p[u] += __shfl_xor(p[u], o);
    }
    if (d == 0) {
      #pragma unroll
      for (int u = 0; u < 4; ++u) sb[(r0 + s0 + u) * 16 + h] = 0.125f * p[u];
    }
  }
}

// ---------------- flash attention: split-KV x4, fixed-max softmax -----------
__global__ __launch_bounds__(256) void attn_k(const __bf16* __restrict__ qg,
    const __bf16* __restrict__ kg, const __bf16* __restrict__ vtg,
    float* __restrict__ o_part, float* __restrict__ l_part) {
  __shared__ __bf16 sK[2][64 * 64];
  __shared__ __bf16 sVt[2][64 * 64];
  __shared__ __bf16 sP[4][16 * 64];
  const int pair = blockIdx.x, j4 = blockIdx.y, hh = blockIdx.z;
  const int tid = threadIdx.x, lane = tid & 63, w = tid >> 6;
  const int quad = lane >> 4, l16 = lane & 15;
  const int srow = tid >> 3;
  const int sg = (tid & 7) ^ (srow & 7);
  __bf16* sPw = sP[w];

  auto stage = [&](int kt) {
    int b = kt & 1;
    const __bf16* gK = kg + (size_t)(kt * 64 + srow) * 1024 + hh * 64 + sg * 8;
    const __bf16* gV = vtg + (size_t)(hh * 64 + srow) * 2048 + kt * 64 + sg * 8;
    GLD16(gK, sK[b] + tid * 8);
    GLD16(gK + (size_t)32 * 1024, sK[b] + tid * 8 + 2048);
    GLD16(gV, sVt[b] + tid * 8);
    GLD16(gV + (size_t)32 * 2048, sVt[b] + tid * 8 + 2048);
  };

  for (int phase = 0; phase < 2; ++phase) {
    const int qt = phase ? 31 - pair : pair;
    const int q0 = qt * 64;
    const int n = qt + 1;
    const int kb = (j4 * n) >> 2, ke = ((j4 + 1) * n) >> 2;
    bf16x8 qf[2];
    #pragma unroll
    for (int kk = 0; kk < 2; ++kk)
      qf[kk] = *(const bf16x8*)(qg + (size_t)(q0 + w * 16 + l16) * 1024 + hh * 64 + kk * 32 + quad * 8);
    f32x4 accO[4] = {};
    float l_[4] = {0.f, 0.f, 0.f, 0.f};   // lane-local partial sums

    __syncthreads();                 // seal previous phase's buffer reads
    if (kb < ke) stage(kb);

    for (int kt = kb; kt < ke; ++kt) {
      __syncthreads();               // implicit vmcnt(0): buf[kt&1] ready;
                                     // seals buf[(kt+1)&1] (last read kt-1)
      SCHED_FENCE();
      if (kt + 1 < ke) stage(kt + 1);
      SCHED_FENCE();
      const __bf16* cK = sK[kt & 1];
      const __bf16* cV = sVt[kt & 1];

      f32x4 s4[4];
      #pragma unroll
      for (int nt = 0; nt < 4; ++nt) {
        int r = nt * 16 + l16;
        bf16x8 b0 = *(const bf16x8*)(cK + r * 64 + ((quad ^ (r & 7)) * 8));
        bf16x8 b1 = *(const bf16x8*)(cK + r * 64 + (((4 + quad) ^ (r & 7)) * 8));
        f32x4 sa = {0.f, 0.f, 0.f, 0.f};
        sa = __builtin_amdgcn_mfma_f32_16x16x32_bf16(qf[0], b0, sa, 0, 0, 0);
        sa = __builtin_amdgcn_mfma_f32_16x16x32_bf16(qf[1], b1, sa, 0, 0, 0);
        s4[nt] = sa;
      }
      if (kt == qt) {
        #pragma unroll
        for (int nt = 0; nt < 4; ++nt)
          #pragma unroll
          for (int r = 0; r < 4; ++r)
            if (nt * 16 + l16 > w * 16 + quad * 4 + r) s4[nt][r] = -INFINITY;
      }
      // fixed-max softmax: p = exp(s - 1); accumulate l lane-locally
      float p[4][4];
      #pragma unroll
      for (int nt = 0; nt < 4; ++nt)
        #pragma unroll
        for (int r = 0; r < 4; ++r)
          p[nt][r] = __expf(s4[nt][r] - 1.0f);
      #pragma unroll
      for (int r = 0; r < 4; ++r)
        l_[r] += (p[0][r] + p[1][r]) + (p[2][r] + p[3][r]);
      #pragma unroll
      for (int nt = 0; nt < 4; ++nt)
        #pragma unroll
        for (int r = 0; r < 4; ++r) {
          int row = quad * 4 + r, col = nt * 16 + l16;
          sPw[row * 64 + (col ^ ((row & 7) << 3))] = (__bf16)p[nt][r];
        }
      #pragma unroll
      for (int kk = 0; kk < 2; ++kk) {
        bf16x8 a = *(const bf16x8*)(sPw + l16 * 64 + (((kk * 4 + quad) ^ (l16 & 7)) * 8));
        #pragma unroll
        for (int nt = 0; nt < 4; ++nt) {
          int vr = nt * 16 + l16;
          bf16x8 bv = *(const bf16x8*)(cV + vr * 64 + (((kk * 4 + quad) ^ (vr & 7)) * 8));
          accO[nt] = __builtin_amdgcn_mfma_f32_16x16x32_bf16(a, bv, accO[nt], 0, 0, 0);
        }
      }
      // no trailing barrier: sP is wave-private; K/V buffers are ring-2 sealed
    }
    // one 16-lane reduce of l per phase (was per tile)
    #pragma unroll
    for (int o = 1; o < 16; o <<= 1)
      #pragma unroll
      for (int r = 0; r < 4; ++r) l_[r] += __shfl_xor(l_[r], o);
    #pragma unroll
    for (int r = 0; r < 4; ++r) {
      int grow = q0 + w * 16 + quad * 4 + r;
      if (l16 == 0)
        l_part[((size_t)j4 * 2048 + grow) * 16 + hh] = l_[r];
      #pragma unroll
      for (int nt = 0; nt < 4; ++nt)
        o_part[((size_t)j4 * 2048 + grow) * 1024 + hh * 64 + nt * 16 + l16] = accO[nt][r];
    }
  }
}

// ---------------- merge 4 KV-partials -> y into concat (stride 5120) --------
__global__ __launch_bounds__(256) void attnmerge_k(const float* __restrict__ o_part,
    const float* __restrict__ l_part, const float* __restrict__ sbr,
    const float* __restrict__ pl2s, __bf16* __restrict__ yo) {
  int idx = blockIdx.x * 256 + threadIdx.x;
  int s = idx >> 8, rem = idx & 255;
  int h = rem >> 4, dg = (rem & 15) * 4;
  float den = 0.f;
  float4 acc = {0.f, 0.f, 0.f, 0.f};
  #pragma unroll
  for (int j = 0; j < 4; ++j) {
    den += l_part[((size_t)j * 2048 + s) * 16 + h];
    float4 o = *(const float4*)(o_part + ((size_t)j * 2048 + s) * 1024 + h * 64 + dg);
    acc.x += o.x; acc.y += o.y; acc.z += o.z; acc.w += o.w;
  }
  float sc = pl2s[0] / den;
  float add = sbr[s * 16 + h];
  __bf16* yp = yo + (size_t)s * 5120 + h * 64 + dg;
  yp[0] = (__bf16)(sc * acc.x + add);
  yp[1] = (__bf16)(sc * acc.y + add);
  yp[2] = (__bf16)(sc * acc.z + add);
  yp[3] = (__bf16)(sc * acc.w + add);
}

extern "C" void kernel_launch(void* const* d_in, const int* in_sizes, int n_in,
                              void* d_out, int out_size, void* d_ws, size_t ws_size,
                              hipStream_t stream) {
  (void)in_sizes; (void)n_in; (void)out_size; (void)ws_size;
  const float* hs   = (const float*)d_in[0];
  const float* Wq   = (const float*)d_in[1];
  const float* Wk   = (const float*)d_in[2];
  const float* Wv   = (const float*)d_in[3];
  const float* Wqb  = (const float*)d_in[4];
  const float* Wkb  = (const float*)d_in[5];
  const float* Wo   = (const float*)d_in[6];
  const float* bo   = (const float*)d_in[7];
  const float* W1   = (const float*)d_in[8];
  const float* b1   = (const float*)d_in[9];
  const float* W2   = (const float*)d_in[10];
  const float* b2   = (const float*)d_in[11];
  const float* plam = (const float*)d_in[12];
  const float* pl2s = (const float*)d_in[13];
  float* out = (float*)d_out;
  char* ws = (char*)d_ws;

  size_t off = 0;
  auto alloc = [&](size_t bytes) { char* p = ws + off; off += (bytes + 255) & ~(size_t)255; return p; };
  __bf16* Wt5    = (__bf16*)alloc((size_t)5 * 1024 * 1024 * 2);
  __bf16* WoW2t  = (__bf16*)alloc((size_t)1024 * 5120 * 2);   // [n][k], k: Wo 0..1023, W2 1024..5119
  __bf16* W1t    = (__bf16*)alloc((size_t)8192 * 1024 * 2);   // packed xp/gate 32-col interleave
  __bf16* xbf    = (__bf16*)alloc((size_t)2048 * 1024 * 2);
  __bf16* concat = (__bf16*)alloc((size_t)2048 * 5120 * 2);   // [y | ffin] bf16
  float*  proj  = (float*)alloc((size_t)2048 * 5120 * 4);     // o_part / gpart scratch
  float*  qbf32 = (float*)alloc((size_t)2048 * 1024 * 4);
  float*  kbf32 = (float*)alloc((size_t)2048 * 1024 * 4);
  __bf16* qbf   = (__bf16*)alloc((size_t)2048 * 1024 * 2);
  __bf16* kbf   = (__bf16*)alloc((size_t)2048 * 1024 * 2);
  float*  o_part = proj;                                      // 4 x 8 MB
  float*  l_part = qbf32;                                     // 512 KB (after sbrow2)
  float*  gpart  = proj;                                      // 4 x 8 MB (after attnmerge)
  __bf16* vtbf  = (__bf16*)alloc((size_t)1024 * 2048 * 2);
  float*  sbrow = (float*)alloc((size_t)2048 * 16 * 4);
  float*  tsum  = (float*)alloc((size_t)64 * 16 * 64 * 4);
  float*  tsum8 = (float*)alloc((size_t)256 * 16 * 64 * 4);

  // merged weight repack
  repack_k<<<18432, 256, 0, stream>>>(Wq, Wk, Wv, Wqb, Wkb, Wo, W2, W1,
                                      Wt5, WoW2t, W1t);

  rmsnorm_k<<<2048, 256, 0, stream>>>(hs, xbf);
  // QKV GEMM: fused l2norm+RoPE epilogue + direct V^T store
  gemm_qkv_k<<<dim3(40, 16), 256, 0, stream>>>(xbf, Wt5, qbf, kbf,
                                               qbf32, kbf32, vtbf);
  kbsum_k<<<dim3(64, 16), 256, 0, stream>>>(kbf32, tsum, tsum8);
  sbrow2_k<<<dim3(64, 16), 256, 0, stream>>>(qbf32, kbf32, tsum, tsum8, sbrow);
  attn_k<<<dim3(16, 4, 16), 256, 0, stream>>>(qbf, kbf, vtbf, o_part, l_part);
  attnmerge_k<<<2048, 256, 0, stream>>>(o_part, l_part, sbrow, pl2s, concat);
  // fused FFN1 + bias + SwiGLU -> concat cols 1024..5119 (256x256 ring-4, 2-phase)
  ffn1silu_k<<<dim3(32, 8), 512, 0, stream>>>(xbf, W1t, b1, concat);
  // merged (Wo + FFN2): [y|ffin] @ [Wo;W2], K=5120, split-K x4 -> partials
  gemm_partk_k<<<dim3(8, 16, 4), 256, 0, stream>>>(concat, WoW2t, gpart, 1024, 5120);
  // out = Σ partials + (bo+b2) + lam*h
  combine_k<<<2048, 256, 0, stream>>>(gpart, b2, bo, hs, plam, out);
}